// Round 3
// baseline (1931.169 us; speedup 1.0000x reference)
//
#include <hip/hip_runtime.h>
#include <float.h>
#include <math.h>

// Problem: z (32,256,32,32) f32, W (8192,256) f32.
// Outputs flat: z_q [0,8388608) | loss [8388608] | index [8388609,8421377) | perp [8421377]
#define OUT_LOSS 8388608
#define OUT_IDX  8388609
#define OUT_PERP 8421377

// Workspace layout (bytes)
#define WS_WT    0u          // float[2097152]  Wt[c][j] transposed codebook
#define WS_S     8388608u    // float[32768]    ||z_n||^2, numpy-pairwise f32
#define WS_B     8519680u    // float[8192]     ||W_j||^2, numpy-pairwise f32
#define WS_IDX   8552448u    // int[32768]
#define WS_HIST  8683520u    // int[8192]
#define WS_LOSS  8716288u    // double

__global__ void k_zero(int* __restrict__ hist, double* __restrict__ loss) {
  const int i = blockIdx.x * 256 + threadIdx.x;
  if (i < 8192) hist[i] = 0;
  else if (i == 8192) *loss = 0.0;
}

// Wt[c][j] = W[j][c]; coalesced writes
__global__ void k_wt(const float* __restrict__ W, float* __restrict__ Wt) {
  const int o = blockIdx.x * 256 + threadIdx.x;   // grid 8192*256 = 2M
  const int c = o >> 13, j = o & 8191;
  Wt[o] = W[(size_t)j * 256 + c];
}

// numpy pairwise sum of squares for n=256 (two 128-blocks, 8 accumulators).
// Exactly mirrors numpy's pairwise_sum: square is a separate rounded multiply.
__device__ __forceinline__ float np_sumsq256(const float* __restrict__ base,
                                             const int stride) {
  float h[2];
#pragma unroll
  for (int half = 0; half < 2; ++half) {
    const float* a = base + (size_t)(half * 128) * stride;
    float r[8];
#pragma unroll
    for (int k = 0; k < 8; ++k) {
      const float v = a[(size_t)k * stride];
      r[k] = __fmul_rn(v, v);
    }
    for (int i = 8; i < 128; i += 8) {
#pragma unroll
      for (int k = 0; k < 8; ++k) {
        const float v = a[(size_t)(i + k) * stride];
        r[k] = __fadd_rn(r[k], __fmul_rn(v, v));
      }
    }
    h[half] = __fadd_rn(
        __fadd_rn(__fadd_rn(r[0], r[1]), __fadd_rn(r[2], r[3])),
        __fadd_rn(__fadd_rn(r[4], r[5]), __fadd_rn(r[6], r[7])));
  }
  return __fadd_rn(h[0], h[1]);
}

// S_n = np.sum(zf*zf, axis=1) per pixel (channel stride 1024)
__global__ __launch_bounds__(256) void k_sz(const float* __restrict__ z,
                                            float* __restrict__ S) {
  const int n = blockIdx.x * 256 + threadIdx.x;   // grid 128
  const int b = n >> 10, p = n & 1023;
  S[n] = np_sumsq256(z + (size_t)b * 262144 + p, 1024);
}

// B_j = np.sum(W*W, axis=1) per code (contiguous row)
__global__ __launch_bounds__(256) void k_wsq(const float* __restrict__ W,
                                             float* __restrict__ B) {
  const int j = blockIdx.x * 256 + threadIdx.x;   // grid 32
  B[j] = np_sumsq256(W + (size_t)j * 256, 1);
}

// Main pass: bit-exact replication of the numpy f32 distance + argmin.
//   C_nj: single-accumulator fmaf chain, k ascending 0..255 (BLAS microkernel order)
//   d    = fl( fl(S_n + B_j) - 2*C_nj )   (2*C exact)
//   argmin with first-occurrence tie-break (np.argmin semantics)
// Block: 32 pixels; 32 tiles of 256 codes; thread = 4 pixels x 8 consecutive codes.
__global__ __launch_bounds__(256) void k_main(const float* __restrict__ z,
    const float* __restrict__ Wt, const float* __restrict__ S,
    const float* __restrict__ B, int* __restrict__ idxb) {
  __shared__ __align__(16) float zs[32][32];    // [k][px]   4 KB
  __shared__ __align__(16) float ws[32][256];   // [k][code] 32 KB (reused for merge)
  const int t  = threadIdx.x;
  const int pg = t & 7;          // pixel group: pixels pg*4 .. pg*4+3
  const int cg = t >> 3;         // code group (0..31): codes cg*8 .. cg*8+7 of tile
  const int n0 = blockIdx.x << 5;   // grid 1024 blocks * 32 px
  const int b  = n0 >> 10;
  const int p0 = n0 & 1023;         // block never spans a batch (32 | 1024)
  const float* zb = z + (size_t)b * 262144 + p0;   // + c*1024 + px

  const float4 s4 = *(const float4*)&S[n0 + (pg << 2)];
  const float spx[4] = {s4.x, s4.y, s4.z, s4.w};

  float m1[4]; int i1[4];
#pragma unroll
  for (int i = 0; i < 4; ++i) { m1[i] = FLT_MAX; i1[i] = 0; }

  const int zr_ = t >> 3;            // z stage: 32 rows x 8 float4
  const int zc_ = (t & 7) << 2;
  const int wr_ = t >> 6;            // w stage: 4 rows/pass x 64 float4
  const int wc_ = (t & 63) << 2;

  for (int nt = 0; nt < 32; ++nt) {   // 256 codes per tile
    const int c0 = nt << 8;
    float acc[4][8];
#pragma unroll
    for (int i = 0; i < 4; ++i)
#pragma unroll
      for (int j = 0; j < 8; ++j) acc[i][j] = 0.f;

    for (int kc = 0; kc < 8; ++kc) {  // K = 256 in chunks of 32, k strictly ascending
      const int kb = kc << 5;
      __syncthreads();
      *(float4*)&zs[zr_][zc_] =
          *(const float4*)&zb[(size_t)(kb + zr_) * 1024 + zc_];
#pragma unroll
      for (int r = 0; r < 8; ++r) {
        const int row = wr_ + (r << 2);
        *(float4*)&ws[row][wc_] =
            *(const float4*)&Wt[(size_t)(kb + row) * 8192 + c0 + wc_];
      }
      __syncthreads();
#pragma unroll
      for (int k = 0; k < 32; ++k) {
        const float4 z4 = *(const float4*)&zs[k][pg << 2];
        const float4 wA = *(const float4*)&ws[k][cg << 3];
        const float4 wB = *(const float4*)&ws[k][(cg << 3) + 4];
        const float zv[4] = {z4.x, z4.y, z4.z, z4.w};
        const float wv[8] = {wA.x, wA.y, wA.z, wA.w, wB.x, wB.y, wB.z, wB.w};
#pragma unroll
        for (int i = 0; i < 4; ++i)
#pragma unroll
          for (int j = 0; j < 8; ++j)
            acc[i][j] = __builtin_fmaf(zv[i], wv[j], acc[i][j]);
      }
    }
    // epilogue: d = fl(fl(S+B) - 2*C); per-thread codes ascend -> strict < = first occurrence
#pragma unroll
    for (int j = 0; j < 8; ++j) {
      const int code = c0 + (cg << 3) + j;
      const float bj = B[code];
#pragma unroll
      for (int i = 0; i < 4; ++i) {
        const float d = __fsub_rn(__fadd_rn(spx[i], bj),
                                  __fmul_rn(2.f, acc[i][j]));
        if (d < m1[i]) { m1[i] = d; i1[i] = code; }
      }
    }
  }
  // LDS merge with lowest-index tie-break (np.argmin first occurrence)
  __syncthreads();
  float* sm1 = &ws[0][0];            // 32*33 floats
  int*   si  = (int*)(sm1 + 1056);
#pragma unroll
  for (int i = 0; i < 4; ++i) {
    const int p = (pg << 2) + i;
    sm1[p * 33 + cg] = m1[i];
    si [p * 33 + cg] = i1[i];
  }
  __syncthreads();
  if (t < 32) {
    float bm = sm1[t * 33]; int bi = si[t * 33];
    for (int g2 = 1; g2 < 32; ++g2) {
      const float v = sm1[t * 33 + g2];
      const int  vi = si [t * 33 + g2];
      if (v < bm || (v == bm && vi < bi)) { bm = v; bi = vi; }
    }
    idxb[n0 + t] = bi;
  }
}

// z_q gather (with STE rounding emulation) + loss + histogram + index output
__global__ __launch_bounds__(256) void k_zq(const float* __restrict__ z,
    const float* __restrict__ W, const int* __restrict__ idxb,
    float* __restrict__ out, double* __restrict__ loss, int* __restrict__ hist) {
  __shared__ float red[256];
  const int t = threadIdx.x;
  const int tx = t & 63, ty = t >> 6;        // 64 pixels x 4 channel-groups
  const int n0 = blockIdx.x << 6;            // grid 512
  const int n = n0 + tx;
  const int b = n >> 10;
  const int p = n & 1023;
  const int myidx = idxb[n];
  const float* wrow = W + (size_t)myidx * 256;
  float lsum = 0.f;
#pragma unroll 4
  for (int cc = 0; cc < 64; ++cc) {
    const int c = ty * 64 + cc;
    const float q = wrow[c];
    const size_t off = (size_t)b * 262144 + (size_t)c * 1024 + p;
    const float zv = z[off];
    const float d = __fsub_rn(q, zv);
    lsum = __builtin_fmaf(d, d, lsum);
    out[off] = __fadd_rn(zv, d);             // STE: fl(z + fl(q - z))
  }
  red[t] = lsum;
  __syncthreads();
  for (int o = 128; o > 0; o >>= 1) {
    if (t < o) red[t] += red[t + o];
    __syncthreads();
  }
  if (t == 0) atomicAdd(loss, (double)red[0]);
  if (ty == 0) atomicAdd(&hist[myidx], 1);
  if (ty == 1) out[OUT_IDX + n] = (float)myidx;
}

__global__ void k_final(const int* __restrict__ hist,
                        const double* __restrict__ loss,
                        float* __restrict__ out) {
  __shared__ double sh[256];
  const int t = threadIdx.x;
  double s = 0.0;
  for (int j = t; j < 8192; j += 256) {
    const double e = (double)hist[j] / 32768.0;
    s += e * log(e + 1e-10);
  }
  sh[t] = s;
  __syncthreads();
  for (int off = 128; off > 0; off >>= 1) {
    if (t < off) sh[t] += sh[t + off];
    __syncthreads();
  }
  if (t == 0) {
    out[OUT_PERP] = (float)exp(-sh[0]);
    out[OUT_LOSS] = (float)(1.25 * (*loss) / 8388608.0);
  }
}

extern "C" void kernel_launch(void* const* d_in, const int* in_sizes, int n_in,
                              void* d_out, int out_size, void* d_ws, size_t ws_size,
                              hipStream_t stream) {
  const float* z = (const float*)d_in[0];
  const float* W = (const float*)d_in[1];
  float* out = (float*)d_out;
  char* ws = (char*)d_ws;
  float*  Wt   = (float*)(ws + WS_WT);
  float*  S    = (float*)(ws + WS_S);
  float*  B    = (float*)(ws + WS_B);
  int*    idxb = (int*)(ws + WS_IDX);
  int*    hist = (int*)(ws + WS_HIST);
  double* loss = (double*)(ws + WS_LOSS);

  hipLaunchKernelGGL(k_zero,  dim3(33),   dim3(256), 0, stream, hist, loss);
  hipLaunchKernelGGL(k_wt,    dim3(8192), dim3(256), 0, stream, W, Wt);
  hipLaunchKernelGGL(k_sz,    dim3(128),  dim3(256), 0, stream, z, S);
  hipLaunchKernelGGL(k_wsq,   dim3(32),   dim3(256), 0, stream, W, B);
  hipLaunchKernelGGL(k_main,  dim3(1024), dim3(256), 0, stream, z, Wt, S, B, idxb);
  hipLaunchKernelGGL(k_zq,    dim3(512),  dim3(256), 0, stream, z, W, idxb, out, loss, hist);
  hipLaunchKernelGGL(k_final, dim3(1),    dim3(256), 0, stream, hist, loss, out);
}